// Round 8
// baseline (1612.880 us; speedup 1.0000x reference)
//
#include <hip/hip_runtime.h>
#include <hip/hip_cooperative_groups.h>
#include <hip/hip_fp16.h>
#include <math.h>

namespace cg = cooperative_groups;

// Problem constants (match reference)
#define BB 8
#define SS 2048
#define TT 2048
#define ITERS 20
#define NEG_EPS_INV -10.0f     // -1/EPSILON
#define NWAVE 8                // 512 threads/block
#define RPW 2                  // rows per wave per chunk
#define NCHUNK 4
#define ROWS (NWAVE * RPW * NCHUNK)   // 64 rows per block
#define NTILE (SS / ROWS)             // 32 tiles -> grid 32*8 = 256 blocks
#define TINYF 1.17549435e-38f

typedef float vfloat4 __attribute__((ext_vector_type(4)));

__device__ __forceinline__ float4 fma4v(float a, float4 x, float4 y) {
    return make_float4(fmaf(a, x.x, y.x), fmaf(a, x.y, y.y),
                       fmaf(a, x.z, y.z), fmaf(a, x.w, y.w));
}
__device__ __forceinline__ float4 max4(float4 a, float4 b) {
    return make_float4(fmaxf(a.x, b.x), fmaxf(a.y, b.y),
                       fmaxf(a.z, b.z), fmaxf(a.w, b.w));
}
__device__ __forceinline__ float hmax4(float4 a) {
    return fmaxf(fmaxf(a.x, a.y), fmaxf(a.z, a.w));
}
__device__ __forceinline__ float hsum4(float4 a) {
    return (a.x + a.y) + (a.z + a.w);
}
__device__ __forceinline__ float4 exp4m(float4 x, float m) {
    return make_float4(__expf(x.x - m), __expf(x.y - m),
                       __expf(x.z - m), __expf(x.w - m));
}
__device__ __forceinline__ uint h2u(__half2 h) {
    union { __half2 h; uint u; } c; c.h = h; return c.u;
}
__device__ __forceinline__ __half2 u2h(uint u) {
    union { __half2 h; uint u; } c; c.u = u; return c.h;
}
__device__ __forceinline__ uint2 pack4(float4 f) {
    uint2 r;
    r.x = h2u(__float22half2_rn(make_float2(f.x, f.y)));
    r.y = h2u(__float22half2_rn(make_float2(f.z, f.w)));
    return r;
}
__device__ __forceinline__ float4 unpack4(uint2 u) {
    float2 a = __half22float2(u2h(u.x));
    float2 b = __half22float2(u2h(u.y));
    return make_float4(a.x, a.y, b.x, b.y);
}
__device__ __forceinline__ void nt_store4(float4 v, float* p) {
    vfloat4 x = {v.x, v.y, v.z, v.w};
    __builtin_nontemporal_store(x, reinterpret_cast<vfloat4*>(p));
}

__global__ __launch_bounds__(256) void init_logs(const float* __restrict__ nu,
                                                 float* __restrict__ log_nu,
                                                 float* __restrict__ log_v) {
    int i = blockIdx.x * 256 + threadIdx.x;  // grid = BB*TT/256
    log_nu[i] = __logf(fmaxf(nu[i], TINYF));
    log_v[i] = 0.0f;
}

// Persistent cooperative kernel: all 20 Sinkhorn iterations.
// Block (tile,b) owns 64 rows x 2048 cols of cost[b], processed as 4 chunks
// of 16 rows (2 rows/wave; row LSE fully in-wave). Column partials accumulate
// in the wave's private LDS plane; cross-wave reduce writes one P plane.
// grid.sync(); blocks 0..31 fold the 32 P planes per column into log_v;
// grid.sync(); next iteration.
__global__ __launch_bounds__(512, 2) void sinkhorn_loop(
        const float* __restrict__ cost, uint2* __restrict__ c16,
        const float* __restrict__ mu, const float* __restrict__ log_nu,
        float* __restrict__ log_u, float* __restrict__ log_v,
        float* __restrict__ P) {
    cg::grid_group gg = cg::this_grid();
    int t = threadIdx.x;
    int w = t >> 6, l = t & 63;
    int bid = blockIdx.x;
    int tile = bid & (NTILE - 1);
    int b = bid >> 5;                 // / NTILE

    __shared__ float4 lds[NWAVE][512];   // 64 KB: one 2048-col plane per wave

    for (int it = 0; it < ITERS; ++it) {
        const float4* v4 = (const float4*)(log_v + (size_t)b * TT);
        float4 vv[8];
#pragma unroll
        for (int i = 0; i < 8; ++i) vv[i] = v4[i * 64 + l];

        // zero this wave's private accumulator plane (no barrier needed)
#pragma unroll
        for (int i = 0; i < 8; ++i) lds[w][i * 64 + l] = make_float4(0.f, 0.f, 0.f, 0.f);

#pragma unroll
        for (int c = 0; c < NCHUNK; ++c) {
            int r0 = tile * ROWS + c * (NWAVE * RPW) + w * RPW;
            size_t rowbase = (size_t)(b * SS + r0) * TT;

            float4 x0[8], x1[8];
            if (it == 0) {
                const float4* c4 = (const float4*)(cost + rowbase);
                uint2* cw = c16 + rowbase / 4;    // uint2 = 4 halves
#pragma unroll
                for (int i = 0; i < 8; ++i) x0[i] = c4[i * 64 + l];
#pragma unroll
                for (int i = 0; i < 8; ++i) x1[i] = c4[512 + i * 64 + l];
#pragma unroll
                for (int i = 0; i < 8; ++i) {
                    cw[i * 64 + l] = pack4(x0[i]);
                    cw[512 + i * 64 + l] = pack4(x1[i]);
                }
            } else {
                const uint2* cr = c16 + rowbase / 4;
#pragma unroll
                for (int i = 0; i < 8; ++i) x0[i] = unpack4(cr[i * 64 + l]);
#pragma unroll
                for (int i = 0; i < 8; ++i) x1[i] = unpack4(cr[512 + i * 64 + l]);
            }
#pragma unroll
            for (int i = 0; i < 8; ++i) {
                x0[i] = fma4v(NEG_EPS_INV, x0[i], vv[i]);
                x1[i] = fma4v(NEG_EPS_INV, x1[i], vv[i]);
            }

            // row max (in-wave butterfly)
            float4 a0 = x0[0], a1 = x1[0];
#pragma unroll
            for (int i = 1; i < 8; ++i) { a0 = max4(a0, x0[i]); a1 = max4(a1, x1[i]); }
            float m0 = hmax4(a0), m1 = hmax4(a1);
#pragma unroll
            for (int off = 1; off < 64; off <<= 1) {
                m0 = fmaxf(m0, __shfl_xor(m0, off));
                m1 = fmaxf(m1, __shfl_xor(m1, off));
            }

            // e = exp(x - M) in place; row sums
            float ps0 = 0.0f, ps1 = 0.0f;
#pragma unroll
            for (int i = 0; i < 8; ++i) {
                x0[i] = exp4m(x0[i], m0);
                x1[i] = exp4m(x1[i], m1);
                ps0 += hsum4(x0[i]);
                ps1 += hsum4(x1[i]);
            }
#pragma unroll
            for (int off = 1; off < 64; off <<= 1) {
                ps0 += __shfl_xor(ps0, off);
                ps1 += __shfl_xor(ps1, off);
            }

            // g = mu/ssum;  u = log(g) - M
            float g0 = mu[b * SS + r0] / ps0;
            float g1 = mu[b * SS + r0 + 1] / ps1;
            if (l == 0) {
                log_u[b * SS + r0]     = __logf(fmaxf(g0, TINYF)) - m0;
                log_u[b * SS + r0 + 1] = __logf(fmaxf(g1, TINYF)) - m1;
            }

            // accumulate column partial into the wave's LDS plane
#pragma unroll
            for (int i = 0; i < 8; ++i) {
                float4 o = lds[w][i * 64 + l];
                o.x = fmaf(g0, x0[i].x, fmaf(g1, x1[i].x, o.x));
                o.y = fmaf(g0, x0[i].y, fmaf(g1, x1[i].y, o.y));
                o.z = fmaf(g0, x0[i].z, fmaf(g1, x1[i].z, o.z));
                o.w = fmaf(g0, x0[i].w, fmaf(g1, x1[i].w, o.w));
                lds[w][i * 64 + l] = o;
            }
        }
        __syncthreads();

        // cross-wave reduce 8 planes -> this block's P plane
        float4* P4 = (float4*)(P + ((size_t)(b * NTILE + tile)) * TT);
        float4 s = lds[0][t];
#pragma unroll
        for (int w2 = 1; w2 < NWAVE; ++w2) {
            float4 q = lds[w2][t];
            s.x += q.x; s.y += q.y; s.z += q.z; s.w += q.w;
        }
        P4[t] = s;

        gg.sync();

        // combine: thread g (blocks 0..31) owns one (b,col)
        int g = bid * 512 + t;
        if (g < BB * TT) {
            int gb = g >> 11, col = g & (TT - 1);
            const float* Pc = P + (size_t)gb * NTILE * TT + col;
            float tot = 0.0f;
#pragma unroll 8
            for (int t2 = 0; t2 < NTILE; ++t2) tot += Pc[(size_t)t2 * TT];
            log_v[g] = log_nu[g] + log_v[g] - __logf(fmaxf(tot, TINYF));
        }

        gg.sync();
    }
}

// transport = exp(log_pi), log_pi = log_u + (-cost/eps) + log_v  (fp16 cost cache)
__global__ __launch_bounds__(256) void finalize(const uint2* __restrict__ c16,
                                                const float* __restrict__ log_u,
                                                const float* __restrict__ log_v,
                                                float* __restrict__ transport,
                                                float* __restrict__ log_pi) {
    int i = blockIdx.x * 256 + threadIdx.x;  // float4 index
    int flat = i * 4;
    int row = flat >> 11;                    // / T
    int t = flat & (TT - 1);
    int b = row >> 11;                       // / S

    float lu = log_u[row];
    float4 lv = *reinterpret_cast<const float4*>(log_v + (size_t)b * TT + t);
    float4 c = unpack4(c16[((size_t)row * TT + t) / 4]);

    float4 lp;
    lp.x = fmaf(NEG_EPS_INV, c.x, lu + lv.x);
    lp.y = fmaf(NEG_EPS_INV, c.y, lu + lv.y);
    lp.z = fmaf(NEG_EPS_INV, c.z, lu + lv.z);
    lp.w = fmaf(NEG_EPS_INV, c.w, lu + lv.w);

    float4 tr;
    tr.x = __expf(lp.x);
    tr.y = __expf(lp.y);
    tr.z = __expf(lp.z);
    tr.w = __expf(lp.w);

    nt_store4(tr, transport + (size_t)row * TT + t);
    nt_store4(lp, log_pi + (size_t)row * TT + t);
}

extern "C" void kernel_launch(void* const* d_in, const int* in_sizes, int n_in,
                              void* d_out, int out_size, void* d_ws, size_t ws_size,
                              hipStream_t stream) {
    const float* cost = (const float*)d_in[0];
    const float* mu = (const float*)d_in[1];
    const float* nu = (const float*)d_in[2];

    float* out = (float*)d_out;
    float* transport = out;
    float* log_pi = out + (size_t)BB * SS * TT;

    // Scratch layout in d_ws: vectors, P planes, fp16 cost cache.
    float* ws = (float*)d_ws;
    float* log_u = ws;                       // 16K floats
    float* log_v = ws + 16384;               // 16K floats
    float* log_nu = ws + 32768;              // 16K floats
    float* P = ws + (1 << 20);               // 4 MB offset; BB*NTILE*TT fl = 2 MB
    uint2* c16 = (uint2*)(ws + (1 << 23));   // 32 MB offset; B*S*T halves = 67 MB

    hipLaunchKernelGGL(init_logs, dim3(BB * TT / 256), dim3(256), 0, stream,
                       nu, log_nu, log_v);

    void* args[] = {(void*)&cost, (void*)&c16, (void*)&mu, (void*)&log_nu,
                    (void*)&log_u, (void*)&log_v, (void*)&P};
    hipLaunchCooperativeKernel(reinterpret_cast<void*>(sinkhorn_loop),
                               dim3(NTILE * BB), dim3(512), args, 0, stream);

    hipLaunchKernelGGL(finalize, dim3(BB * SS * TT / 4 / 256), dim3(256), 0, stream,
                       c16, log_u, log_v, transport, log_pi);
}